// Round 3
// baseline (497.218 us; speedup 1.0000x reference)
//
#include <hip/hip_runtime.h>
#include <stdint.h>

// Problem constants
#define B_SZ   32
#define NIN    2312
#define NHID   512
#define NOUT   10
#define T_SZ   350
#define NW32   73                 // ceil(2312/32) bitmask words per input column
#define NW64   8                  // 512/64 ballot words per hidden column
#define NHALF  256                // output half-width for L2-resident W1
#define NROW   2313               // NIN + 1 dummy zero row (branch-free padding)

// psp (SRM) kernel eps[n] = CS * n * DS^n, DS = exp(-0.1), CS = e/10
#define DS_D   0.9048374180359595
#define CS_D   0.2718281828459045
#define D100_D 4.5399929762484854e-05   // exp(-10) = DS^100
// refractory recurrence in fp32, exactly like the reference scan
#define DREF_F 0.36787944117144233f     // exp(-1)
#define CREF_F -54.36563656918091f      // -2*10*e

#define NPF 14                    // prefetch ring depth (350 = 14*25)

// ---------------------------------------------------------------------------
// K12: fused bitpack (blocks 0..2335) + W1 pack (blocks 2336..3503) +
//      dummy-zero-row fill (block 3504).
__global__ __launch_bounds__(384) void k12(const float* __restrict__ x,
                                           const float* __restrict__ W1,
                                           uint32_t* __restrict__ bits1,
                                           float* __restrict__ W1s) {
    const int bid = blockIdx.x;
    const int tid = threadIdx.x;
    if (bid < NW32 * B_SZ) {
        // --- k1: bitpack spikeInput [B, NIN, T] -> bits1[(b*T + t)*73 + w]
        const int w = bid % NW32;
        const int b = bid / NW32;
        if (tid < 175) {
            const int t2 = tid * 2;
            uint32_t bitsA = 0, bitsB = 0;
            const float* p = x + ((size_t)(b * NIN + (w << 5))) * T_SZ + t2;
#pragma unroll
            for (int j = 0; j < 32; ++j) {
                int i = (w << 5) + j;
                if (i < NIN) {
                    float2 v = *(const float2*)(p + (size_t)j * T_SZ);
                    if (v.x > 0.5f) bitsA |= (1u << j);
                    if (v.y > 0.5f) bitsB |= (1u << j);
                }
            }
            bits1[(size_t)(b * T_SZ + t2) * NW32 + w] = bitsA;
            bits1[(size_t)(b * T_SZ + t2 + 1) * NW32 + w] = bitsB;
        }
    } else if (bid < NW32 * B_SZ + NW32 * 16) {
        // --- k2: pack W1 [512, 2312] -> W1s[h][i][256], h = o>>8
        __shared__ float tile[32][33];
        const int bb = bid - NW32 * B_SZ;
        const int i0 = (bb % NW32) * 32, o0 = (bb / NW32) * 32;
        const int tx = tid & 31, ty = tid >> 5;  // ty 0..11
#pragma unroll
        for (int r = 0; r < 3; ++r) {
            int row = ty + 12 * r;
            if (row < 32) {
                int o = o0 + row, i = i0 + tx;
                if (i < NIN) tile[row][tx] = W1[(size_t)o * NIN + i];
            }
        }
        __syncthreads();
#pragma unroll
        for (int r = 0; r < 3; ++r) {
            int row = ty + 12 * r;
            if (row < 32) {
                int i = i0 + row, o = o0 + tx;
                if (i < NIN)
                    W1s[((size_t)(o >> 8) * NROW + i) * NHALF + (o & 255)] = tile[tx][row];
            }
        }
    } else {
        // --- dummy zero row i = NIN for both halves
        if (tid < NHALF) {
            W1s[((size_t)0 * NROW + NIN) * NHALF + tid] = 0.0f;
            W1s[((size_t)1 * NROW + NIN) * NHALF + tid] = 0.0f;
        }
    }
}

// ---------------------------------------------------------------------------
// K3: sparse dense1, half-split for L2 residency. Single-wave shfl prefix
// scan (5 barriers total), branch-free 4-deep pipelined row loop via dummy
// zero-row padding. Writes z1ct[(b*8+oc)*350 + t][64].
__global__ __launch_bounds__(256) void k3_dense1(const uint32_t* __restrict__ bits1,
                                                 const float* __restrict__ W1s,
                                                 float* __restrict__ z1ct) {
    __shared__ uint32_t words[128];
    __shared__ uint16_t pfx[80];
    __shared__ uint16_t idxbuf[NIN + 16];
    __shared__ float red[3][NHALF];
    __shared__ float fin[NHALF];

    const int bt = blockIdx.x;          // b*350 + t
    const int h = blockIdx.y;           // 0 or 1
    const int tid = threadIdx.x;
    const int wv = tid >> 6, lane = tid & 63;

    if (tid < 128) words[tid] = (tid < NW32) ? bits1[(size_t)bt * NW32 + tid] : 0u;
    __syncthreads();

    if (wv == 0) {
        uint32_t w0 = words[lane];
        uint32_t w1 = words[lane + 64];
        int p0 = __popc(w0), p1 = __popc(w1);
        int s0 = p0, s1 = p1;
#pragma unroll
        for (int off = 1; off < 64; off <<= 1) {
            int u0 = __shfl_up(s0, off);
            int u1 = __shfl_up(s1, off);
            if (lane >= off) { s0 += u0; s1 += u1; }
        }
        int tot0 = __shfl(s0, 63);
        pfx[lane] = (uint16_t)(s0 - p0);
        if (lane < 9) pfx[lane + 64] = (uint16_t)(tot0 + s1 - p1);
        if (lane == 8) pfx[73] = (uint16_t)(tot0 + s1);   // ntot
    }
    __syncthreads();

    const int ntot = pfx[73];
    const int npad = (ntot + 15) & ~15;
    if (tid < NW32) {
        uint32_t m = words[tid];
        int p = pfx[tid];
        while (m) {
            int j = __builtin_ctz(m);
            m &= m - 1;
            idxbuf[p++] = (uint16_t)((tid << 5) + j);
        }
    }
    if (tid >= 240) {                   // pad to multiple of 16 with zero row
        int k = tid - 240;
        if (ntot + k < npad) idxbuf[ntot + k] = (uint16_t)NIN;
    }
    __syncthreads();

    const float* Wh = W1s + (size_t)h * NROW * NHALF;
    float4 acc = make_float4(0.f, 0.f, 0.f, 0.f);
    for (int r = wv; r < npad; r += 16) {
        // same per-wave row order as before (r += 4), but 4 loads in flight
        int i0 = idxbuf[r], i1 = idxbuf[r + 4], i2 = idxbuf[r + 8], i3 = idxbuf[r + 12];
        float4 v0 = ((const float4*)(Wh + (size_t)i0 * NHALF))[lane];
        float4 v1 = ((const float4*)(Wh + (size_t)i1 * NHALF))[lane];
        float4 v2 = ((const float4*)(Wh + (size_t)i2 * NHALF))[lane];
        float4 v3 = ((const float4*)(Wh + (size_t)i3 * NHALF))[lane];
        acc.x += v0.x; acc.y += v0.y; acc.z += v0.z; acc.w += v0.w;
        acc.x += v1.x; acc.y += v1.y; acc.z += v1.z; acc.w += v1.w;
        acc.x += v2.x; acc.y += v2.y; acc.z += v2.z; acc.w += v2.w;
        acc.x += v3.x; acc.y += v3.y; acc.z += v3.z; acc.w += v3.w;
    }
    if (wv > 0) ((float4*)red[wv - 1])[lane] = acc;
    __syncthreads();
    if (wv == 0) {
        float4 a1 = ((float4*)red[0])[lane];
        float4 a2 = ((float4*)red[1])[lane];
        float4 a3 = ((float4*)red[2])[lane];
        acc.x = ((acc.x + a1.x) + a2.x) + a3.x;
        acc.y = ((acc.y + a1.y) + a2.y) + a3.y;
        acc.z = ((acc.z + a1.z) + a2.z) + a3.z;
        acc.w = ((acc.w + a1.w) + a2.w) + a3.w;
        ((float4*)fin)[lane] = acc;
    }
    __syncthreads();
    const int och = (h << 8) + tid;
    const int oc = och >> 6, l6 = och & 63;
    const int b = bt / T_SZ, t = bt - b * T_SZ;
    z1ct[((size_t)(b * NW64 + oc) * T_SZ + t) * 64 + l6] = fin[tid];
}

// ---------------------------------------------------------------------------
// K4: fused psp-IIR (fp64, exact truncated FIR via delayed tail) + refractory
// spike scan (fp32 = reference recurrence). 14-deep register prefetch rings.
__global__ __launch_bounds__(64) void k4_fir_scan1(const float* __restrict__ z1ct,
                                                   uint64_t* __restrict__ s1bits) {
    const int lane = threadIdx.x;
    const int bc = blockIdx.x;          // b*8 + oc
    const float* base = z1ct + (size_t)bc * T_SZ * 64 + lane;
    uint64_t* outp = s1bits + (size_t)bc * T_SZ;
    double A = 0.0, Bs = 0.0, A2 = 0.0, Bs2 = 0.0;
    float ra = 0.0f, rb = 0.0f;
    const double TAIL = D100_D * CS_D;
    float xb[NPF], xdb[NPF];
#pragma unroll
    for (int i = 0; i < NPF; ++i) {
        xb[i] = base[(size_t)i * 64];
        xdb[i] = 0.0f;
    }
    for (int t0 = 0; t0 < T_SZ; t0 += NPF) {
#pragma unroll
        for (int i = 0; i < NPF; ++i) {
            const int t = t0 + i;
            float x = xb[i], xd = xdb[i];
            const int tn = t + NPF;
            xb[i] = (tn < T_SZ) ? base[(size_t)tn * 64] : 0.0f;
            const int td = tn - 100;
            xdb[i] = (td >= 0) ? base[(size_t)td * 64] : 0.0f;
            Bs = DS_D * Bs + DS_D * A;
            A = DS_D * A + (double)x;
            Bs2 = DS_D * Bs2 + DS_D * A2;
            A2 = DS_D * A2 + (double)xd;
            double y = CS_D * Bs - TAIL * (Bs2 + 100.0 * A2);
            float u = (float)y + CREF_F * rb;
            float s = (u >= 10.0f) ? 1.0f : 0.0f;
            float ran = DREF_F * ra + s;
            float rbn = DREF_F * rb + DREF_F * ra;
            ra = ran; rb = rbn;
            uint64_t mball = __ballot(s != 0.0f);
            if (lane == 0) outp[t] = mball;
        }
    }
}

// ---------------------------------------------------------------------------
// K56: fused dense2 + psp-IIR + refractory scan, one block per batch b.
// z2 computed inline from s1 ballot words (LDS-staged); t-100 delayed tap
// served by a 100-deep LDS ring. Writes d_out [B, NOUT, T].
__global__ __launch_bounds__(64) void k56_dense2_scan(const uint64_t* __restrict__ s1bits,
                                                      const float* __restrict__ W2,
                                                      float* __restrict__ out) {
    __shared__ float W2s[NHID * NOUT];      // [c][o], 20 KB
    __shared__ uint64_t sw[NPF][NW64];      // staged ballot words, 896 B
    __shared__ float ring[64][100];         // z2 delay line per lane, 25.6 KB
    const int b = blockIdx.x;
    const int lane = threadIdx.x;

    for (int k = lane; k < NHID * NOUT; k += 64) {
        int c = k / NOUT, o = k - c * NOUT;
        W2s[k] = W2[(size_t)o * NHID + c];
    }
    for (int k = 0; k < 100; ++k) ring[lane][k] = 0.0f;
    __syncthreads();

    double A = 0.0, Bs = 0.0, A2 = 0.0, Bs2 = 0.0;
    float ra = 0.0f, rb = 0.0f;
    const double TAIL = D100_D * CS_D;
    int pos = 0;
    for (int t0 = 0; t0 < T_SZ; t0 += NPF) {
        for (int k = lane; k < NPF * NW64; k += 64) {
            int j = k >> 3, wvv = k & 7;
            sw[j][wvv] = s1bits[(size_t)(b * NW64 + wvv) * T_SZ + t0 + j];
        }
        __syncthreads();
#pragma unroll
        for (int j = 0; j < NPF; ++j) {
            const int t = t0 + j;
            float acc = 0.0f;
            if (lane < NOUT) {
#pragma unroll
                for (int wvv = 0; wvv < NW64; ++wvv) {
                    uint64_t m = sw[j][wvv];
                    while (m) {
                        int c = __builtin_ctzll(m);
                        m &= m - 1;
                        acc += W2s[((wvv << 6) + c) * NOUT + lane];
                    }
                }
            }
            float xd = ring[lane][pos];     // z2[t-100] (0 for t<100)
            ring[lane][pos] = acc;
            pos = (pos == 99) ? 0 : pos + 1;
            Bs = DS_D * Bs + DS_D * A;
            A = DS_D * A + (double)acc;
            Bs2 = DS_D * Bs2 + DS_D * A2;
            A2 = DS_D * A2 + (double)xd;
            double y = CS_D * Bs - TAIL * (Bs2 + 100.0 * A2);
            float u = (float)y + CREF_F * rb;
            float s = (u >= 10.0f) ? 1.0f : 0.0f;
            float ran = DREF_F * ra + s;
            float rbn = DREF_F * rb + DREF_F * ra;
            ra = ran; rb = rbn;
            if (lane < NOUT) out[((size_t)b * NOUT + lane) * T_SZ + t] = s;
        }
        __syncthreads();
    }
}

// ---------------------------------------------------------------------------
extern "C" void kernel_launch(void* const* d_in, const int* in_sizes, int n_in,
                              void* d_out, int out_size, void* d_ws, size_t ws_size,
                              hipStream_t stream) {
    const float* spikeInput = (const float*)d_in[0];  // [32, 2312, 350]
    const float* W1 = (const float*)d_in[1];          // [512, 2312]
    const float* W2 = (const float*)d_in[2];          // [10, 512]
    float* out = (float*)d_out;                       // [32, 10, 350]

    char* ws = (char*)d_ws;
    float* W1s = (float*)(ws + 0);                        //  4,737,024 B (2313 rows x 2 halves)
    uint32_t* bits1 = (uint32_t*)(ws + 4737024);          //  3,270,400 B
    float* z1ct = (float*)(ws + 8007424);                 // 22,937,600 B
    uint64_t* s1bits = (uint64_t*)(ws + 30945024);        //    716,800 B
    // total: 31,661,824 B

    k12<<<NW32 * B_SZ + NW32 * 16 + 1, 384, 0, stream>>>(spikeInput, W1, bits1, W1s);
    k3_dense1<<<dim3(B_SZ * T_SZ, 2), 256, 0, stream>>>(bits1, W1s, z1ct);
    k4_fir_scan1<<<B_SZ * NW64, 64, 0, stream>>>(z1ct, s1bits);
    k56_dense2_scan<<<B_SZ, 64, 0, stream>>>(s1bits, W2, out);
}

// Round 4
// 357.144 us; speedup vs baseline: 1.3922x; 1.3922x over previous
//
#include <hip/hip_runtime.h>
#include <stdint.h>

// Problem constants
#define B_SZ   32
#define NIN    2312
#define NHID   512
#define NOUT   10
#define T_SZ   350
#define NW32   73                 // ceil(2312/32) bitmask words per input column
#define NW64   8                  // 512/64 ballot words per hidden column
#define NHALF  256                // output half-width for L2-resident W1
#define NROW   2313               // NIN + 1 dummy zero row (branch-free padding)

// psp (SRM) kernel eps[n] = CS * n * DS^n, DS = exp(-0.1), CS = e/10
#define DS_D   0.9048374180359595
#define CS_D   0.2718281828459045
#define D100_D 4.5399929762484854e-05   // exp(-10) = DS^100
// refractory recurrence in fp32, exactly like the reference scan
#define DREF_F 0.36787944117144233f     // exp(-1)
#define CREF_F -54.36563656918091f      // -2*10*e

#define NPF 14                    // prefetch ring depth (350 = 14*25)

// ---------------------------------------------------------------------------
// K12: fused bitpack (blocks 0..2335) + W1 pack (blocks 2336..3503) +
//      dummy-zero-row fill (block 3504).
__global__ __launch_bounds__(384) void k12(const float* __restrict__ x,
                                           const float* __restrict__ W1,
                                           uint32_t* __restrict__ bits1,
                                           float* __restrict__ W1s) {
    const int bid = blockIdx.x;
    const int tid = threadIdx.x;
    if (bid < NW32 * B_SZ) {
        // --- k1: bitpack spikeInput [B, NIN, T] -> bits1[(b*T + t)*73 + w]
        const int w = bid % NW32;
        const int b = bid / NW32;
        if (tid < 175) {
            const int t2 = tid * 2;
            uint32_t bitsA = 0, bitsB = 0;
            const float* p = x + ((size_t)(b * NIN + (w << 5))) * T_SZ + t2;
#pragma unroll
            for (int j = 0; j < 32; ++j) {
                int i = (w << 5) + j;
                if (i < NIN) {
                    float2 v = *(const float2*)(p + (size_t)j * T_SZ);
                    if (v.x > 0.5f) bitsA |= (1u << j);
                    if (v.y > 0.5f) bitsB |= (1u << j);
                }
            }
            bits1[(size_t)(b * T_SZ + t2) * NW32 + w] = bitsA;
            bits1[(size_t)(b * T_SZ + t2 + 1) * NW32 + w] = bitsB;
        }
    } else if (bid < NW32 * B_SZ + NW32 * 16) {
        // --- k2: pack W1 [512, 2312] -> W1s[h][i][256], h = o>>8
        __shared__ float tile[32][33];
        const int bb = bid - NW32 * B_SZ;
        const int i0 = (bb % NW32) * 32, o0 = (bb / NW32) * 32;
        const int tx = tid & 31, ty = tid >> 5;  // ty 0..11
#pragma unroll
        for (int r = 0; r < 3; ++r) {
            int row = ty + 12 * r;
            if (row < 32) {
                int o = o0 + row, i = i0 + tx;
                if (i < NIN) tile[row][tx] = W1[(size_t)o * NIN + i];
            }
        }
        __syncthreads();
#pragma unroll
        for (int r = 0; r < 3; ++r) {
            int row = ty + 12 * r;
            if (row < 32) {
                int i = i0 + row, o = o0 + tx;
                if (i < NIN)
                    W1s[((size_t)(o >> 8) * NROW + i) * NHALF + (o & 255)] = tile[tx][row];
            }
        }
    } else {
        // --- dummy zero row i = NIN for both halves
        if (tid < NHALF) {
            W1s[((size_t)0 * NROW + NIN) * NHALF + tid] = 0.0f;
            W1s[((size_t)1 * NROW + NIN) * NHALF + tid] = 0.0f;
        }
    }
}

// ---------------------------------------------------------------------------
// K3: sparse dense1, half-split for L2 residency. Single-wave shfl prefix
// scan, branch-free 4-deep pipelined row loop via dummy zero-row padding.
// Writes z1ct[(b*8+oc)*350 + t][64].
__global__ __launch_bounds__(256) void k3_dense1(const uint32_t* __restrict__ bits1,
                                                 const float* __restrict__ W1s,
                                                 float* __restrict__ z1ct) {
    __shared__ uint32_t words[128];
    __shared__ uint16_t pfx[80];
    __shared__ uint16_t idxbuf[NIN + 16];
    __shared__ float red[3][NHALF];
    __shared__ float fin[NHALF];

    const int bt = blockIdx.x;          // b*350 + t
    const int h = blockIdx.y;           // 0 or 1
    const int tid = threadIdx.x;
    const int wv = tid >> 6, lane = tid & 63;

    if (tid < 128) words[tid] = (tid < NW32) ? bits1[(size_t)bt * NW32 + tid] : 0u;
    __syncthreads();

    if (wv == 0) {
        uint32_t w0 = words[lane];
        uint32_t w1 = words[lane + 64];
        int p0 = __popc(w0), p1 = __popc(w1);
        int s0 = p0, s1 = p1;
#pragma unroll
        for (int off = 1; off < 64; off <<= 1) {
            int u0 = __shfl_up(s0, off);
            int u1 = __shfl_up(s1, off);
            if (lane >= off) { s0 += u0; s1 += u1; }
        }
        int tot0 = __shfl(s0, 63);
        pfx[lane] = (uint16_t)(s0 - p0);
        if (lane < 9) pfx[lane + 64] = (uint16_t)(tot0 + s1 - p1);
        if (lane == 8) pfx[73] = (uint16_t)(tot0 + s1);   // ntot
    }
    __syncthreads();

    const int ntot = pfx[73];
    const int npad = (ntot + 15) & ~15;
    if (tid < NW32) {
        uint32_t m = words[tid];
        int p = pfx[tid];
        while (m) {
            int j = __builtin_ctz(m);
            m &= m - 1;
            idxbuf[p++] = (uint16_t)((tid << 5) + j);
        }
    }
    if (tid >= 240) {                   // pad to multiple of 16 with zero row
        int k = tid - 240;
        if (ntot + k < npad) idxbuf[ntot + k] = (uint16_t)NIN;
    }
    __syncthreads();

    const float* Wh = W1s + (size_t)h * NROW * NHALF;
    float4 acc = make_float4(0.f, 0.f, 0.f, 0.f);
    for (int r = wv; r < npad; r += 16) {
        int i0 = idxbuf[r], i1 = idxbuf[r + 4], i2 = idxbuf[r + 8], i3 = idxbuf[r + 12];
        float4 v0 = ((const float4*)(Wh + (size_t)i0 * NHALF))[lane];
        float4 v1 = ((const float4*)(Wh + (size_t)i1 * NHALF))[lane];
        float4 v2 = ((const float4*)(Wh + (size_t)i2 * NHALF))[lane];
        float4 v3 = ((const float4*)(Wh + (size_t)i3 * NHALF))[lane];
        acc.x += v0.x; acc.y += v0.y; acc.z += v0.z; acc.w += v0.w;
        acc.x += v1.x; acc.y += v1.y; acc.z += v1.z; acc.w += v1.w;
        acc.x += v2.x; acc.y += v2.y; acc.z += v2.z; acc.w += v2.w;
        acc.x += v3.x; acc.y += v3.y; acc.z += v3.z; acc.w += v3.w;
    }
    if (wv > 0) ((float4*)red[wv - 1])[lane] = acc;
    __syncthreads();
    if (wv == 0) {
        float4 a1 = ((float4*)red[0])[lane];
        float4 a2 = ((float4*)red[1])[lane];
        float4 a3 = ((float4*)red[2])[lane];
        acc.x = ((acc.x + a1.x) + a2.x) + a3.x;
        acc.y = ((acc.y + a1.y) + a2.y) + a3.y;
        acc.z = ((acc.z + a1.z) + a2.z) + a3.z;
        acc.w = ((acc.w + a1.w) + a2.w) + a3.w;
        ((float4*)fin)[lane] = acc;
    }
    __syncthreads();
    const int och = (h << 8) + tid;
    const int oc = och >> 6, l6 = och & 63;
    const int b = bt / T_SZ, t = bt - b * T_SZ;
    z1ct[((size_t)(b * NW64 + oc) * T_SZ + t) * 64 + l6] = fin[tid];
}

// ---------------------------------------------------------------------------
// K4: fused psp-IIR (fp64, exact truncated FIR via delayed tail) + refractory
// spike scan (fp32 = reference recurrence). 14-deep register prefetch rings.
__global__ __launch_bounds__(64) void k4_fir_scan1(const float* __restrict__ z1ct,
                                                   uint64_t* __restrict__ s1bits) {
    const int lane = threadIdx.x;
    const int bc = blockIdx.x;          // b*8 + oc
    const float* base = z1ct + (size_t)bc * T_SZ * 64 + lane;
    uint64_t* outp = s1bits + (size_t)bc * T_SZ;
    double A = 0.0, Bs = 0.0, A2 = 0.0, Bs2 = 0.0;
    float ra = 0.0f, rb = 0.0f;
    const double TAIL = D100_D * CS_D;
    float xb[NPF], xdb[NPF];
#pragma unroll
    for (int i = 0; i < NPF; ++i) {
        xb[i] = base[(size_t)i * 64];
        xdb[i] = 0.0f;
    }
    for (int t0 = 0; t0 < T_SZ; t0 += NPF) {
#pragma unroll
        for (int i = 0; i < NPF; ++i) {
            const int t = t0 + i;
            float x = xb[i], xd = xdb[i];
            const int tn = t + NPF;
            xb[i] = (tn < T_SZ) ? base[(size_t)tn * 64] : 0.0f;
            const int td = tn - 100;
            xdb[i] = (td >= 0) ? base[(size_t)td * 64] : 0.0f;
            Bs = DS_D * Bs + DS_D * A;
            A = DS_D * A + (double)x;
            Bs2 = DS_D * Bs2 + DS_D * A2;
            A2 = DS_D * A2 + (double)xd;
            double y = CS_D * Bs - TAIL * (Bs2 + 100.0 * A2);
            float u = (float)y + CREF_F * rb;
            float s = (u >= 10.0f) ? 1.0f : 0.0f;
            float ran = DREF_F * ra + s;
            float rbn = DREF_F * rb + DREF_F * ra;
            ra = ran; rb = rbn;
            uint64_t mball = __ballot(s != 0.0f);
            if (lane == 0) outp[t] = mball;
        }
    }
}

// ---------------------------------------------------------------------------
// K5: sparse dense2: z2t[t*320 + b*10+o] = sum_c s1[b,c,t] * W2[o,c]
// (massively parallel; the round-3 per-batch fusion of this was 185 us at
//  0.35% occupancy -- keep this embarrassingly parallel form)
__global__ __launch_bounds__(256) void k5_dense2(const uint64_t* __restrict__ s1bits,
                                                 const float* __restrict__ W2,
                                                 float* __restrict__ z2t) {
    __shared__ float W2s[NHID * NOUT];  // [c][o], 20 KB
    for (int k = threadIdx.x; k < NHID * NOUT; k += 256) {
        int c = k / NOUT, o = k - c * NOUT;
        W2s[k] = W2[(size_t)o * NHID + c];
    }
    __syncthreads();
    int idx = blockIdx.x * 256 + threadIdx.x;   // t*320 + bo
    if (idx >= T_SZ * B_SZ * NOUT) return;
    int t = idx / (B_SZ * NOUT);
    int bo = idx - t * (B_SZ * NOUT);
    int b = bo / NOUT;
    int o = bo - b * NOUT;
    float acc = 0.f;
    const uint64_t* bp = s1bits + (size_t)b * NW64 * T_SZ + t;
#pragma unroll
    for (int wv = 0; wv < NW64; ++wv) {
        uint64_t m = bp[(size_t)wv * T_SZ];
        while (m) {
            int j = __builtin_ctzll(m);
            m &= m - 1;
            acc += W2s[((wv << 6) + j) * NOUT + o];
        }
    }
    z2t[idx] = acc;
}

// ---------------------------------------------------------------------------
// K6: fused psp-IIR + refractory scan, layer 2, with prefetch rings.
// Writes d_out [B, NOUT, T].
__global__ __launch_bounds__(64) void k6_fir_scan2(const float* __restrict__ z2t,
                                                   float* __restrict__ out) {
    const int bo = blockIdx.x * 64 + threadIdx.x;  // 0..319
    const float* base = z2t + bo;                  // stride 320 floats over t
    double A = 0.0, Bs = 0.0, A2 = 0.0, Bs2 = 0.0;
    float ra = 0.0f, rb = 0.0f;
    const double TAIL = D100_D * CS_D;
    float* op = out + (size_t)bo * T_SZ;
    float xb[NPF], xdb[NPF];
#pragma unroll
    for (int i = 0; i < NPF; ++i) {
        xb[i] = base[(size_t)i * (B_SZ * NOUT)];
        xdb[i] = 0.0f;
    }
    for (int t0 = 0; t0 < T_SZ; t0 += NPF) {
#pragma unroll
        for (int i = 0; i < NPF; ++i) {
            const int t = t0 + i;
            float x = xb[i], xd = xdb[i];
            const int tn = t + NPF;
            xb[i] = (tn < T_SZ) ? base[(size_t)tn * (B_SZ * NOUT)] : 0.0f;
            const int td = tn - 100;
            xdb[i] = (td >= 0) ? base[(size_t)td * (B_SZ * NOUT)] : 0.0f;
            Bs = DS_D * Bs + DS_D * A;
            A = DS_D * A + (double)x;
            Bs2 = DS_D * Bs2 + DS_D * A2;
            A2 = DS_D * A2 + (double)xd;
            double y = CS_D * Bs - TAIL * (Bs2 + 100.0 * A2);
            float u = (float)y + CREF_F * rb;
            float s = (u >= 10.0f) ? 1.0f : 0.0f;
            float ran = DREF_F * ra + s;
            float rbn = DREF_F * rb + DREF_F * ra;
            ra = ran; rb = rbn;
            op[t] = s;
        }
    }
}

// ---------------------------------------------------------------------------
extern "C" void kernel_launch(void* const* d_in, const int* in_sizes, int n_in,
                              void* d_out, int out_size, void* d_ws, size_t ws_size,
                              hipStream_t stream) {
    const float* spikeInput = (const float*)d_in[0];  // [32, 2312, 350]
    const float* W1 = (const float*)d_in[1];          // [512, 2312]
    const float* W2 = (const float*)d_in[2];          // [10, 512]
    float* out = (float*)d_out;                       // [32, 10, 350]

    char* ws = (char*)d_ws;
    float* W1s = (float*)(ws + 0);                        //  4,737,024 B (2313 rows x 2 halves)
    uint32_t* bits1 = (uint32_t*)(ws + 4737024);          //  3,270,400 B
    float* z1ct = (float*)(ws + 8007424);                 // 22,937,600 B
    uint64_t* s1bits = (uint64_t*)(ws + 30945024);        //    716,800 B
    // z2t aliases bits1's region: bits1 is dead after k3, z2t written by k5.
    float* z2t = (float*)(ws + 4737024);                  //    448,000 B (alias)
    // total: 31,661,824 B

    k12<<<NW32 * B_SZ + NW32 * 16 + 1, 384, 0, stream>>>(spikeInput, W1, bits1, W1s);
    k3_dense1<<<dim3(B_SZ * T_SZ, 2), 256, 0, stream>>>(bits1, W1s, z1ct);
    k4_fir_scan1<<<B_SZ * NW64, 64, 0, stream>>>(z1ct, s1bits);
    k5_dense2<<<(T_SZ * B_SZ * NOUT + 255) / 256, 256, 0, stream>>>(s1bits, W2, z2t);
    k6_fir_scan2<<<(B_SZ * NOUT) / 64, 64, 0, stream>>>(z2t, out);
}

// Round 5
// 335.664 us; speedup vs baseline: 1.4813x; 1.0640x over previous
//
#include <hip/hip_runtime.h>
#include <stdint.h>

// Problem constants
#define B_SZ   32
#define NIN    2312
#define NHID   512
#define NOUT   10
#define T_SZ   350
#define NW32   73                 // ceil(2312/32) bitmask words per input column
#define NW64   8                  // 512/64 ballot words per hidden column
#define NHALF  256                // output half-width for L2-resident W1
#define NROW   2313               // NIN + 1 dummy zero row (branch-free padding)

// psp (SRM) kernel eps[n] = CS * n * DS^n, DS = exp(-0.1), CS = e/10
#define DS_D   0.9048374180359595
#define CS_D   0.2718281828459045
#define D100_D 4.5399929762484854e-05   // exp(-10) = DS^100
// refractory recurrence in fp32, exactly like the reference scan
#define DREF_F 0.36787944117144233f     // exp(-1)
#define CREF_F -54.36563656918091f      // -2*10*e

// scan chunking: 7 chunks of 50 t-steps; psp-IIR warm-started <=100 steps
// early is EXACT (FIR truncated at 100 taps); refractory burn-in error decays
// e^-n -> < 1e-28 by chunk start (absorbed below fp32 ulp).
#define NCHUNK 7
#define CLEN   50
#define NPF    10                 // prefetch ring depth (50 and 150 both %10==0)

// ---------------------------------------------------------------------------
// K12: fused bitpack (blocks 0..2335) + W1 pack (blocks 2336..3503) +
//      dummy-zero-row fill (block 3504).
__global__ __launch_bounds__(384) void k12(const float* __restrict__ x,
                                           const float* __restrict__ W1,
                                           uint32_t* __restrict__ bits1,
                                           float* __restrict__ W1s) {
    const int bid = blockIdx.x;
    const int tid = threadIdx.x;
    if (bid < NW32 * B_SZ) {
        // --- k1: bitpack spikeInput [B, NIN, T] -> bits1[(b*T + t)*73 + w]
        const int w = bid % NW32;
        const int b = bid / NW32;
        if (tid < 175) {
            const int t2 = tid * 2;
            uint32_t bitsA = 0, bitsB = 0;
            const float* p = x + ((size_t)(b * NIN + (w << 5))) * T_SZ + t2;
#pragma unroll
            for (int j = 0; j < 32; ++j) {
                int i = (w << 5) + j;
                if (i < NIN) {
                    float2 v = *(const float2*)(p + (size_t)j * T_SZ);
                    if (v.x > 0.5f) bitsA |= (1u << j);
                    if (v.y > 0.5f) bitsB |= (1u << j);
                }
            }
            bits1[(size_t)(b * T_SZ + t2) * NW32 + w] = bitsA;
            bits1[(size_t)(b * T_SZ + t2 + 1) * NW32 + w] = bitsB;
        }
    } else if (bid < NW32 * B_SZ + NW32 * 16) {
        // --- k2: pack W1 [512, 2312] -> W1s[h][i][256], h = o>>8
        __shared__ float tile[32][33];
        const int bb = bid - NW32 * B_SZ;
        const int i0 = (bb % NW32) * 32, o0 = (bb / NW32) * 32;
        const int tx = tid & 31, ty = tid >> 5;  // ty 0..11
#pragma unroll
        for (int r = 0; r < 3; ++r) {
            int row = ty + 12 * r;
            if (row < 32) {
                int o = o0 + row, i = i0 + tx;
                if (i < NIN) tile[row][tx] = W1[(size_t)o * NIN + i];
            }
        }
        __syncthreads();
#pragma unroll
        for (int r = 0; r < 3; ++r) {
            int row = ty + 12 * r;
            if (row < 32) {
                int i = i0 + row, o = o0 + tx;
                if (i < NIN)
                    W1s[((size_t)(o >> 8) * NROW + i) * NHALF + (o & 255)] = tile[tx][row];
            }
        }
    } else {
        // --- dummy zero row i = NIN for both halves
        if (tid < NHALF) {
            W1s[((size_t)0 * NROW + NIN) * NHALF + tid] = 0.0f;
            W1s[((size_t)1 * NROW + NIN) * NHALF + tid] = 0.0f;
        }
    }
}

// ---------------------------------------------------------------------------
// K3: sparse dense1, half-split for L2 residency. Single-wave shfl prefix
// scan, branch-free 4-deep pipelined row loop via dummy zero-row padding.
// Writes z1ct[(b*8+oc)*350 + t][64].
__global__ __launch_bounds__(256) void k3_dense1(const uint32_t* __restrict__ bits1,
                                                 const float* __restrict__ W1s,
                                                 float* __restrict__ z1ct) {
    __shared__ uint32_t words[128];
    __shared__ uint16_t pfx[80];
    __shared__ uint16_t idxbuf[NIN + 16];
    __shared__ float red[3][NHALF];
    __shared__ float fin[NHALF];

    const int bt = blockIdx.x;          // b*350 + t
    const int h = blockIdx.y;           // 0 or 1
    const int tid = threadIdx.x;
    const int wv = tid >> 6, lane = tid & 63;

    if (tid < 128) words[tid] = (tid < NW32) ? bits1[(size_t)bt * NW32 + tid] : 0u;
    __syncthreads();

    if (wv == 0) {
        uint32_t w0 = words[lane];
        uint32_t w1 = words[lane + 64];
        int p0 = __popc(w0), p1 = __popc(w1);
        int s0 = p0, s1 = p1;
#pragma unroll
        for (int off = 1; off < 64; off <<= 1) {
            int u0 = __shfl_up(s0, off);
            int u1 = __shfl_up(s1, off);
            if (lane >= off) { s0 += u0; s1 += u1; }
        }
        int tot0 = __shfl(s0, 63);
        pfx[lane] = (uint16_t)(s0 - p0);
        if (lane < 9) pfx[lane + 64] = (uint16_t)(tot0 + s1 - p1);
        if (lane == 8) pfx[73] = (uint16_t)(tot0 + s1);   // ntot
    }
    __syncthreads();

    const int ntot = pfx[73];
    const int npad = (ntot + 15) & ~15;
    if (tid < NW32) {
        uint32_t m = words[tid];
        int p = pfx[tid];
        while (m) {
            int j = __builtin_ctz(m);
            m &= m - 1;
            idxbuf[p++] = (uint16_t)((tid << 5) + j);
        }
    }
    if (tid >= 240) {                   // pad to multiple of 16 with zero row
        int k = tid - 240;
        if (ntot + k < npad) idxbuf[ntot + k] = (uint16_t)NIN;
    }
    __syncthreads();

    const float* Wh = W1s + (size_t)h * NROW * NHALF;
    float4 acc = make_float4(0.f, 0.f, 0.f, 0.f);
    for (int r = wv; r < npad; r += 16) {
        int i0 = idxbuf[r], i1 = idxbuf[r + 4], i2 = idxbuf[r + 8], i3 = idxbuf[r + 12];
        float4 v0 = ((const float4*)(Wh + (size_t)i0 * NHALF))[lane];
        float4 v1 = ((const float4*)(Wh + (size_t)i1 * NHALF))[lane];
        float4 v2 = ((const float4*)(Wh + (size_t)i2 * NHALF))[lane];
        float4 v3 = ((const float4*)(Wh + (size_t)i3 * NHALF))[lane];
        acc.x += v0.x; acc.y += v0.y; acc.z += v0.z; acc.w += v0.w;
        acc.x += v1.x; acc.y += v1.y; acc.z += v1.z; acc.w += v1.w;
        acc.x += v2.x; acc.y += v2.y; acc.z += v2.z; acc.w += v2.w;
        acc.x += v3.x; acc.y += v3.y; acc.z += v3.z; acc.w += v3.w;
    }
    if (wv > 0) ((float4*)red[wv - 1])[lane] = acc;
    __syncthreads();
    if (wv == 0) {
        float4 a1 = ((float4*)red[0])[lane];
        float4 a2 = ((float4*)red[1])[lane];
        float4 a3 = ((float4*)red[2])[lane];
        acc.x = ((acc.x + a1.x) + a2.x) + a3.x;
        acc.y = ((acc.y + a1.y) + a2.y) + a3.y;
        acc.z = ((acc.z + a1.z) + a2.z) + a3.z;
        acc.w = ((acc.w + a1.w) + a2.w) + a3.w;
        ((float4*)fin)[lane] = acc;
    }
    __syncthreads();
    const int och = (h << 8) + tid;
    const int oc = och >> 6, l6 = och & 63;
    const int b = bt / T_SZ, t = bt - b * T_SZ;
    z1ct[((size_t)(b * NW64 + oc) * T_SZ + t) * 64 + l6] = fin[tid];
}

// ---------------------------------------------------------------------------
// K4: fused psp-IIR (fp64, exact truncated FIR via delayed tail) + refractory
// spike scan (fp32 = reference recurrence). CHUNKED over t: 7 chunks of 50
// with <=100-step burn-in (exact; see header note). 1792 waves (7/CU).
__global__ __launch_bounds__(64) void k4_fir_scan1(const float* __restrict__ z1ct,
                                                   uint64_t* __restrict__ s1bits) {
    const int lane = threadIdx.x;
    const int bc = blockIdx.x / NCHUNK;   // b*8 + oc
    const int ck = blockIdx.x % NCHUNK;
    const int tstart = ck * CLEN;
    const int tend = tstart + CLEN;
    const int t0 = (tstart >= 100) ? tstart - 100 : 0;
    const float* base = z1ct + (size_t)bc * T_SZ * 64 + lane;
    uint64_t* outp = s1bits + (size_t)bc * T_SZ;
    double A = 0.0, Bs = 0.0, A2 = 0.0, Bs2 = 0.0;
    float ra = 0.0f, rb = 0.0f;
    const double TAIL = D100_D * CS_D;
    float xb[NPF], xdb[NPF];
#pragma unroll
    for (int i = 0; i < NPF; ++i) {
        int t = t0 + i;
        xb[i] = base[(size_t)t * 64];
        int td = t - 100;
        xdb[i] = (td >= 0) ? base[(size_t)td * 64] : 0.0f;
    }
    for (int tb = t0; tb < tend; tb += NPF) {
#pragma unroll
        for (int i = 0; i < NPF; ++i) {
            const int t = tb + i;
            float x = xb[i], xd = xdb[i];
            const int tn = t + NPF;
            xb[i] = (tn < T_SZ) ? base[(size_t)tn * 64] : 0.0f;
            const int td = tn - 100;
            xdb[i] = (td >= 0) ? base[(size_t)td * 64] : 0.0f;
            Bs = DS_D * Bs + DS_D * A;
            A = DS_D * A + (double)x;
            Bs2 = DS_D * Bs2 + DS_D * A2;
            A2 = DS_D * A2 + (double)xd;
            double y = CS_D * Bs - TAIL * (Bs2 + 100.0 * A2);
            float u = (float)y + CREF_F * rb;
            float s = (u >= 10.0f) ? 1.0f : 0.0f;
            float ran = DREF_F * ra + s;
            float rbn = DREF_F * rb + DREF_F * ra;
            ra = ran; rb = rbn;
            uint64_t mball = __ballot(s != 0.0f);
            if (t >= tstart && lane == 0) outp[t] = mball;
        }
    }
}

// ---------------------------------------------------------------------------
// K5: sparse dense2: z2ct[(bo>>6)*350 + t][bo&63] = sum_c s1[b,c,t] * W2[o,c]
__global__ __launch_bounds__(256) void k5_dense2(const uint64_t* __restrict__ s1bits,
                                                 const float* __restrict__ W2,
                                                 float* __restrict__ z2ct) {
    __shared__ float W2s[NHID * NOUT];  // [c][o], 20 KB
    for (int k = threadIdx.x; k < NHID * NOUT; k += 256) {
        int c = k / NOUT, o = k - c * NOUT;
        W2s[k] = W2[(size_t)o * NHID + c];
    }
    __syncthreads();
    int idx = blockIdx.x * 256 + threadIdx.x;   // t*320 + bo
    if (idx >= T_SZ * B_SZ * NOUT) return;
    int t = idx / (B_SZ * NOUT);
    int bo = idx - t * (B_SZ * NOUT);
    int b = bo / NOUT;
    int o = bo - b * NOUT;
    float acc = 0.f;
    const uint64_t* bp = s1bits + (size_t)b * NW64 * T_SZ + t;
#pragma unroll
    for (int wv = 0; wv < NW64; ++wv) {
        uint64_t m = bp[(size_t)wv * T_SZ];
        while (m) {
            int j = __builtin_ctzll(m);
            m &= m - 1;
            acc += W2s[((wv << 6) + j) * NOUT + o];
        }
    }
    z2ct[((size_t)(bo >> 6) * T_SZ + t) * 64 + (bo & 63)] = acc;
}

// ---------------------------------------------------------------------------
// K6: fused psp-IIR + refractory scan, layer 2, chunked like K4 (35 waves).
// Reads z2ct[g][t][64]; writes d_out [B, NOUT, T].
__global__ __launch_bounds__(64) void k6_fir_scan2(const float* __restrict__ z2ct,
                                                   float* __restrict__ out) {
    const int lane = threadIdx.x;
    const int g = blockIdx.x / NCHUNK;    // bo group 0..4
    const int ck = blockIdx.x % NCHUNK;
    const int tstart = ck * CLEN;
    const int tend = tstart + CLEN;
    const int t0 = (tstart >= 100) ? tstart - 100 : 0;
    const int bo = (g << 6) + lane;       // 0..319
    const float* base = z2ct + (size_t)g * T_SZ * 64 + lane;
    float* op = out + (size_t)bo * T_SZ;
    double A = 0.0, Bs = 0.0, A2 = 0.0, Bs2 = 0.0;
    float ra = 0.0f, rb = 0.0f;
    const double TAIL = D100_D * CS_D;
    float xb[NPF], xdb[NPF];
#pragma unroll
    for (int i = 0; i < NPF; ++i) {
        int t = t0 + i;
        xb[i] = base[(size_t)t * 64];
        int td = t - 100;
        xdb[i] = (td >= 0) ? base[(size_t)td * 64] : 0.0f;
    }
    for (int tb = t0; tb < tend; tb += NPF) {
#pragma unroll
        for (int i = 0; i < NPF; ++i) {
            const int t = tb + i;
            float x = xb[i], xd = xdb[i];
            const int tn = t + NPF;
            xb[i] = (tn < T_SZ) ? base[(size_t)tn * 64] : 0.0f;
            const int td = tn - 100;
            xdb[i] = (td >= 0) ? base[(size_t)td * 64] : 0.0f;
            Bs = DS_D * Bs + DS_D * A;
            A = DS_D * A + (double)x;
            Bs2 = DS_D * Bs2 + DS_D * A2;
            A2 = DS_D * A2 + (double)xd;
            double y = CS_D * Bs - TAIL * (Bs2 + 100.0 * A2);
            float u = (float)y + CREF_F * rb;
            float s = (u >= 10.0f) ? 1.0f : 0.0f;
            float ran = DREF_F * ra + s;
            float rbn = DREF_F * rb + DREF_F * ra;
            ra = ran; rb = rbn;
            if (t >= tstart) op[t] = s;
        }
    }
}

// ---------------------------------------------------------------------------
extern "C" void kernel_launch(void* const* d_in, const int* in_sizes, int n_in,
                              void* d_out, int out_size, void* d_ws, size_t ws_size,
                              hipStream_t stream) {
    const float* spikeInput = (const float*)d_in[0];  // [32, 2312, 350]
    const float* W1 = (const float*)d_in[1];          // [512, 2312]
    const float* W2 = (const float*)d_in[2];          // [10, 512]
    float* out = (float*)d_out;                       // [32, 10, 350]

    char* ws = (char*)d_ws;
    float* W1s = (float*)(ws + 0);                        //  4,737,024 B (2313 rows x 2 halves)
    uint32_t* bits1 = (uint32_t*)(ws + 4737024);          //  3,270,400 B
    float* z1ct = (float*)(ws + 8007424);                 // 22,937,600 B
    uint64_t* s1bits = (uint64_t*)(ws + 30945024);        //    716,800 B
    // z2ct aliases bits1's region: bits1 is dead after k3, z2ct written by k5.
    float* z2ct = (float*)(ws + 4737024);                 //    448,000 B (alias)
    // total: 31,661,824 B

    k12<<<NW32 * B_SZ + NW32 * 16 + 1, 384, 0, stream>>>(spikeInput, W1, bits1, W1s);
    k3_dense1<<<dim3(B_SZ * T_SZ, 2), 256, 0, stream>>>(bits1, W1s, z1ct);
    k4_fir_scan1<<<B_SZ * NW64 * NCHUNK, 64, 0, stream>>>(z1ct, s1bits);
    k5_dense2<<<(T_SZ * B_SZ * NOUT + 255) / 256, 256, 0, stream>>>(s1bits, W2, z2ct);
    k6_fir_scan2<<<5 * NCHUNK, 64, 0, stream>>>(z2ct, out);
}

// Round 6
// 333.848 us; speedup vs baseline: 1.4894x; 1.0054x over previous
//
#include <hip/hip_runtime.h>
#include <stdint.h>

// Problem constants
#define B_SZ   32
#define NIN    2312
#define NHID   512
#define NOUT   10
#define T_SZ   350
#define NW32   73                 // ceil(2312/32) bitmask words per input column
#define NW64   8                  // 512/64 ballot words per hidden column
#define NHALF  256                // output half-width for L2-resident W1
#define NROW   2313               // NIN + 1 dummy zero row (branch-free padding)

// psp (SRM) kernel eps[n] = CS * n * DS^n, DS = exp(-0.1), CS = e/10
#define DS_D   0.9048374180359595
#define CS_D   0.2718281828459045
#define D100_D 4.5399929762484854e-05   // exp(-10) = DS^100
// refractory recurrence in fp32, exactly like the reference scan
#define DREF_F 0.36787944117144233f     // exp(-1)
#define CREF_F -54.36563656918091f      // -2*10*e

// scan chunking: 7 chunks of 50 t-steps; psp-IIR warm-started <=100 steps
// early is EXACT (FIR truncated at 100 taps); refractory burn-in error decays
// e^-n -> < 1e-28 by chunk start (absorbed below fp32 ulp).
#define NCHUNK 7
#define CLEN   50
#define NPF    10                 // prefetch ring depth (50 and 150 both %10==0)

// ---------------------------------------------------------------------------
// K12: fused bitpack (blocks 0..2335) + W1 pack (blocks 2336..3503) +
//      dummy-zero-row fill (block 3504).
// Bitpack rewritten: the 32x350 input tile is CONTIGUOUS in global memory ->
// flat float2 copy to LDS with all 384 lanes (was 175/384 active, scalar-ish),
// then per-t column packing from LDS (2-way bank aliasing = free).
__global__ __launch_bounds__(384) void k12(const float* __restrict__ x,
                                           const float* __restrict__ W1,
                                           uint32_t* __restrict__ bits1,
                                           float* __restrict__ W1s) {
    __shared__ float lds[32 * T_SZ];   // 44.8 KB
    const int bid = blockIdx.x;
    const int tid = threadIdx.x;
    if (bid < NW32 * B_SZ) {
        // --- bitpack: block = (b, w); rows w*32..w*32+rows-1, all t
        const int w = bid % NW32;
        const int b = bid / NW32;
        const int rows = (NIN - (w << 5) < 32) ? (NIN - (w << 5)) : 32;  // 8 for w=72
        const float* base = x + ((size_t)(b * NIN + (w << 5))) * T_SZ;
        const int nf2 = rows * (T_SZ / 2);          // rows*175 float2, contiguous
        for (int f = tid; f < nf2; f += 384)
            ((float2*)lds)[f] = ((const float2*)base)[f];
        __syncthreads();
        if (tid < T_SZ) {
            uint32_t bits = 0;
            for (int j = 0; j < rows; ++j)
                bits |= (lds[j * T_SZ + tid] > 0.5f) ? (1u << j) : 0u;
            bits1[(size_t)(b * T_SZ + tid) * NW32 + w] = bits;
        }
    } else if (bid < NW32 * B_SZ + NW32 * 16) {
        // --- pack W1 [512, 2312] -> W1s[h][i][256], h = o>>8
        float (*tile)[33] = (float (*)[33])lds;
        const int bb = bid - NW32 * B_SZ;
        const int i0 = (bb % NW32) * 32, o0 = (bb / NW32) * 32;
        const int tx = tid & 31, ty = tid >> 5;  // ty 0..11
#pragma unroll
        for (int r = 0; r < 3; ++r) {
            int row = ty + 12 * r;
            if (row < 32) {
                int o = o0 + row, i = i0 + tx;
                if (i < NIN) tile[row][tx] = W1[(size_t)o * NIN + i];
            }
        }
        __syncthreads();
#pragma unroll
        for (int r = 0; r < 3; ++r) {
            int row = ty + 12 * r;
            if (row < 32) {
                int i = i0 + row, o = o0 + tx;
                if (i < NIN)
                    W1s[((size_t)(o >> 8) * NROW + i) * NHALF + (o & 255)] = tile[tx][row];
            }
        }
    } else {
        // --- dummy zero row i = NIN for both halves
        if (tid < NHALF) {
            W1s[((size_t)0 * NROW + NIN) * NHALF + tid] = 0.0f;
            W1s[((size_t)1 * NROW + NIN) * NHALF + tid] = 0.0f;
        }
    }
}

// ---------------------------------------------------------------------------
// K3: sparse dense1, half-split for L2 residency. Single-wave shfl prefix
// scan, branch-free 4-deep pipelined row loop via dummy zero-row padding.
// Writes z1ct[(b*8+oc)*350 + t][64].
__global__ __launch_bounds__(256) void k3_dense1(const uint32_t* __restrict__ bits1,
                                                 const float* __restrict__ W1s,
                                                 float* __restrict__ z1ct) {
    __shared__ uint32_t words[128];
    __shared__ uint16_t pfx[80];
    __shared__ uint16_t idxbuf[NIN + 16];
    __shared__ float red[3][NHALF];
    __shared__ float fin[NHALF];

    const int bt = blockIdx.x;          // b*350 + t
    const int h = blockIdx.y;           // 0 or 1
    const int tid = threadIdx.x;
    const int wv = tid >> 6, lane = tid & 63;

    if (tid < 128) words[tid] = (tid < NW32) ? bits1[(size_t)bt * NW32 + tid] : 0u;
    __syncthreads();

    if (wv == 0) {
        uint32_t w0 = words[lane];
        uint32_t w1 = words[lane + 64];
        int p0 = __popc(w0), p1 = __popc(w1);
        int s0 = p0, s1 = p1;
#pragma unroll
        for (int off = 1; off < 64; off <<= 1) {
            int u0 = __shfl_up(s0, off);
            int u1 = __shfl_up(s1, off);
            if (lane >= off) { s0 += u0; s1 += u1; }
        }
        int tot0 = __shfl(s0, 63);
        pfx[lane] = (uint16_t)(s0 - p0);
        if (lane < 9) pfx[lane + 64] = (uint16_t)(tot0 + s1 - p1);
        if (lane == 8) pfx[73] = (uint16_t)(tot0 + s1);   // ntot
    }
    __syncthreads();

    const int ntot = pfx[73];
    const int npad = (ntot + 15) & ~15;
    if (tid < NW32) {
        uint32_t m = words[tid];
        int p = pfx[tid];
        while (m) {
            int j = __builtin_ctz(m);
            m &= m - 1;
            idxbuf[p++] = (uint16_t)((tid << 5) + j);
        }
    }
    if (tid >= 240) {                   // pad to multiple of 16 with zero row
        int k = tid - 240;
        if (ntot + k < npad) idxbuf[ntot + k] = (uint16_t)NIN;
    }
    __syncthreads();

    const float* Wh = W1s + (size_t)h * NROW * NHALF;
    float4 acc = make_float4(0.f, 0.f, 0.f, 0.f);
    for (int r = wv; r < npad; r += 16) {
        int i0 = idxbuf[r], i1 = idxbuf[r + 4], i2 = idxbuf[r + 8], i3 = idxbuf[r + 12];
        float4 v0 = ((const float4*)(Wh + (size_t)i0 * NHALF))[lane];
        float4 v1 = ((const float4*)(Wh + (size_t)i1 * NHALF))[lane];
        float4 v2 = ((const float4*)(Wh + (size_t)i2 * NHALF))[lane];
        float4 v3 = ((const float4*)(Wh + (size_t)i3 * NHALF))[lane];
        acc.x += v0.x; acc.y += v0.y; acc.z += v0.z; acc.w += v0.w;
        acc.x += v1.x; acc.y += v1.y; acc.z += v1.z; acc.w += v1.w;
        acc.x += v2.x; acc.y += v2.y; acc.z += v2.z; acc.w += v2.w;
        acc.x += v3.x; acc.y += v3.y; acc.z += v3.z; acc.w += v3.w;
    }
    if (wv > 0) ((float4*)red[wv - 1])[lane] = acc;
    __syncthreads();
    if (wv == 0) {
        float4 a1 = ((float4*)red[0])[lane];
        float4 a2 = ((float4*)red[1])[lane];
        float4 a3 = ((float4*)red[2])[lane];
        acc.x = ((acc.x + a1.x) + a2.x) + a3.x;
        acc.y = ((acc.y + a1.y) + a2.y) + a3.y;
        acc.z = ((acc.z + a1.z) + a2.z) + a3.z;
        acc.w = ((acc.w + a1.w) + a2.w) + a3.w;
        ((float4*)fin)[lane] = acc;
    }
    __syncthreads();
    const int och = (h << 8) + tid;
    const int oc = och >> 6, l6 = och & 63;
    const int b = bt / T_SZ, t = bt - b * T_SZ;
    z1ct[((size_t)(b * NW64 + oc) * T_SZ + t) * 64 + l6] = fin[tid];
}

// ---------------------------------------------------------------------------
// K4: fused psp-IIR (fp64, exact truncated FIR via delayed tail) + refractory
// spike scan (fp32 = reference recurrence). CHUNKED over t: 7 chunks of 50
// with <=100-step burn-in (exact; see header note). 1792 waves (7/CU).
__global__ __launch_bounds__(64) void k4_fir_scan1(const float* __restrict__ z1ct,
                                                   uint64_t* __restrict__ s1bits) {
    const int lane = threadIdx.x;
    const int bc = blockIdx.x / NCHUNK;   // b*8 + oc
    const int ck = blockIdx.x % NCHUNK;
    const int tstart = ck * CLEN;
    const int tend = tstart + CLEN;
    const int t0 = (tstart >= 100) ? tstart - 100 : 0;
    const float* base = z1ct + (size_t)bc * T_SZ * 64 + lane;
    uint64_t* outp = s1bits + (size_t)bc * T_SZ;
    double A = 0.0, Bs = 0.0, A2 = 0.0, Bs2 = 0.0;
    float ra = 0.0f, rb = 0.0f;
    const double TAIL = D100_D * CS_D;
    float xb[NPF], xdb[NPF];
#pragma unroll
    for (int i = 0; i < NPF; ++i) {
        int t = t0 + i;
        xb[i] = base[(size_t)t * 64];
        int td = t - 100;
        xdb[i] = (td >= 0) ? base[(size_t)td * 64] : 0.0f;
    }
    for (int tb = t0; tb < tend; tb += NPF) {
#pragma unroll
        for (int i = 0; i < NPF; ++i) {
            const int t = tb + i;
            float x = xb[i], xd = xdb[i];
            const int tn = t + NPF;
            xb[i] = (tn < T_SZ) ? base[(size_t)tn * 64] : 0.0f;
            const int td = tn - 100;
            xdb[i] = (td >= 0) ? base[(size_t)td * 64] : 0.0f;
            Bs = DS_D * Bs + DS_D * A;
            A = DS_D * A + (double)x;
            Bs2 = DS_D * Bs2 + DS_D * A2;
            A2 = DS_D * A2 + (double)xd;
            double y = CS_D * Bs - TAIL * (Bs2 + 100.0 * A2);
            float u = (float)y + CREF_F * rb;
            float s = (u >= 10.0f) ? 1.0f : 0.0f;
            float ran = DREF_F * ra + s;
            float rbn = DREF_F * rb + DREF_F * ra;
            ra = ran; rb = rbn;
            uint64_t mball = __ballot(s != 0.0f);
            if (t >= tstart && lane == 0) outp[t] = mball;
        }
    }
}

// ---------------------------------------------------------------------------
// K5: sparse dense2: z2ct[(bo>>6)*350 + t][bo&63] = sum_c s1[b,c,t] * W2[o,c]
__global__ __launch_bounds__(256) void k5_dense2(const uint64_t* __restrict__ s1bits,
                                                 const float* __restrict__ W2,
                                                 float* __restrict__ z2ct) {
    __shared__ float W2s[NHID * NOUT];  // [c][o], 20 KB
    for (int k = threadIdx.x; k < NHID * NOUT; k += 256) {
        int c = k / NOUT, o = k - c * NOUT;
        W2s[k] = W2[(size_t)o * NHID + c];
    }
    __syncthreads();
    int idx = blockIdx.x * 256 + threadIdx.x;   // t*320 + bo
    if (idx >= T_SZ * B_SZ * NOUT) return;
    int t = idx / (B_SZ * NOUT);
    int bo = idx - t * (B_SZ * NOUT);
    int b = bo / NOUT;
    int o = bo - b * NOUT;
    float acc = 0.f;
    const uint64_t* bp = s1bits + (size_t)b * NW64 * T_SZ + t;
#pragma unroll
    for (int wv = 0; wv < NW64; ++wv) {
        uint64_t m = bp[(size_t)wv * T_SZ];
        while (m) {
            int j = __builtin_ctzll(m);
            m &= m - 1;
            acc += W2s[((wv << 6) + j) * NOUT + o];
        }
    }
    z2ct[((size_t)(bo >> 6) * T_SZ + t) * 64 + (bo & 63)] = acc;
}

// ---------------------------------------------------------------------------
// K6: fused psp-IIR + refractory scan, layer 2, chunked like K4 (35 waves).
// Reads z2ct[g][t][64]; writes d_out [B, NOUT, T].
__global__ __launch_bounds__(64) void k6_fir_scan2(const float* __restrict__ z2ct,
                                                   float* __restrict__ out) {
    const int lane = threadIdx.x;
    const int g = blockIdx.x / NCHUNK;    // bo group 0..4
    const int ck = blockIdx.x % NCHUNK;
    const int tstart = ck * CLEN;
    const int tend = tstart + CLEN;
    const int t0 = (tstart >= 100) ? tstart - 100 : 0;
    const int bo = (g << 6) + lane;       // 0..319
    const float* base = z2ct + (size_t)g * T_SZ * 64 + lane;
    float* op = out + (size_t)bo * T_SZ;
    double A = 0.0, Bs = 0.0, A2 = 0.0, Bs2 = 0.0;
    float ra = 0.0f, rb = 0.0f;
    const double TAIL = D100_D * CS_D;
    float xb[NPF], xdb[NPF];
#pragma unroll
    for (int i = 0; i < NPF; ++i) {
        int t = t0 + i;
        xb[i] = base[(size_t)t * 64];
        int td = t - 100;
        xdb[i] = (td >= 0) ? base[(size_t)td * 64] : 0.0f;
    }
    for (int tb = t0; tb < tend; tb += NPF) {
#pragma unroll
        for (int i = 0; i < NPF; ++i) {
            const int t = tb + i;
            float x = xb[i], xd = xdb[i];
            const int tn = t + NPF;
            xb[i] = (tn < T_SZ) ? base[(size_t)tn * 64] : 0.0f;
            const int td = tn - 100;
            xdb[i] = (td >= 0) ? base[(size_t)td * 64] : 0.0f;
            Bs = DS_D * Bs + DS_D * A;
            A = DS_D * A + (double)x;
            Bs2 = DS_D * Bs2 + DS_D * A2;
            A2 = DS_D * A2 + (double)xd;
            double y = CS_D * Bs - TAIL * (Bs2 + 100.0 * A2);
            float u = (float)y + CREF_F * rb;
            float s = (u >= 10.0f) ? 1.0f : 0.0f;
            float ran = DREF_F * ra + s;
            float rbn = DREF_F * rb + DREF_F * ra;
            ra = ran; rb = rbn;
            if (t >= tstart) op[t] = s;
        }
    }
}

// ---------------------------------------------------------------------------
extern "C" void kernel_launch(void* const* d_in, const int* in_sizes, int n_in,
                              void* d_out, int out_size, void* d_ws, size_t ws_size,
                              hipStream_t stream) {
    const float* spikeInput = (const float*)d_in[0];  // [32, 2312, 350]
    const float* W1 = (const float*)d_in[1];          // [512, 2312]
    const float* W2 = (const float*)d_in[2];          // [10, 512]
    float* out = (float*)d_out;                       // [32, 10, 350]

    char* ws = (char*)d_ws;
    float* W1s = (float*)(ws + 0);                        //  4,737,024 B (2313 rows x 2 halves)
    uint32_t* bits1 = (uint32_t*)(ws + 4737024);          //  3,270,400 B
    float* z1ct = (float*)(ws + 8007424);                 // 22,937,600 B
    uint64_t* s1bits = (uint64_t*)(ws + 30945024);        //    716,800 B
    // z2ct aliases bits1's region: bits1 is dead after k3, z2ct written by k5.
    float* z2ct = (float*)(ws + 4737024);                 //    448,000 B (alias)
    // total: 31,661,824 B

    k12<<<NW32 * B_SZ + NW32 * 16 + 1, 384, 0, stream>>>(spikeInput, W1, bits1, W1s);
    k3_dense1<<<dim3(B_SZ * T_SZ, 2), 256, 0, stream>>>(bits1, W1s, z1ct);
    k4_fir_scan1<<<B_SZ * NW64 * NCHUNK, 64, 0, stream>>>(z1ct, s1bits);
    k5_dense2<<<(T_SZ * B_SZ * NOUT + 255) / 256, 256, 0, stream>>>(s1bits, W2, z2ct);
    k6_fir_scan2<<<5 * NCHUNK, 64, 0, stream>>>(z2ct, out);
}